// Round 1
// 1509.081 us; speedup vs baseline: 1.4111x; 1.4111x over previous
//
#include <hip/hip_runtime.h>
#include <hip/hip_fp16.h>

#define BATCH 32
#define SEQ   1024
#define DIM   512

typedef _Float16 f16x8 __attribute__((ext_vector_type(8)));
typedef float    f32x4 __attribute__((ext_vector_type(4)));
typedef unsigned int u32x4 __attribute__((ext_vector_type(4)));

union UU4 { uint4 s; u32x4 v; };

static __device__ __forceinline__ float tanh_fast(float x) {
    float e = __expf(2.0f * x);
    return 1.0f - 2.0f / (e + 1.0f);
}

// ---------------------------------------------------------------------------
// Pack a 512x512 fp32 row-major W into fp16 MFMA B-fragment layout:
//   Wp[((k>>5)*512 + n)*32 + ((k>>3)&3)*8 + (k&7)] = W[k][n]
// One uint4 per (k-block, col, quad) = the 16x16x32 B fragment, coalesced.
// ---------------------------------------------------------------------------
__global__ void pack_w(const float* __restrict__ W, __half* __restrict__ Wp) {
    int id = blockIdx.x * blockDim.x + threadIdx.x;   // 0 .. 262143
    int n = id & 511;
    int k = id >> 9;
    Wp[((k >> 5) * 512 + n) * 32 + ((k >> 3) & 3) * 8 + (k & 7)] = __float2half(W[k * 512 + n]);
}

// ---------------------------------------------------------------------------
// Kernel 1: xw = x @ W_xh + b (fp16 MFMA 16x16x32, fp32 out). Unchanged.
// ---------------------------------------------------------------------------
__global__ __launch_bounds__(256) void gemm_xw(const float* __restrict__ X,
                                               const __half* __restrict__ Wp,
                                               const float* __restrict__ bias,
                                               float* __restrict__ out) {
    const int nb   = blockIdx.x;
    const int mb   = blockIdx.y;
    const int lane = threadIdx.x & 63;
    const int wave = threadIdx.x >> 6;
    const int q    = lane >> 4;
    const int r16  = lane & 15;
    const int row  = mb * 64 + wave * 16 + r16;

    const float4* Xf4  = (const float4*)X;
    const uint4*  WpU4 = (const uint4*)Wp;

    f32x4 acc[4];
    #pragma unroll
    for (int nt = 0; nt < 4; ++nt) acc[nt] = (f32x4){0.f, 0.f, 0.f, 0.f};

    #pragma unroll 4
    for (int kb = 0; kb < 16; ++kb) {
        float4 a0 = Xf4[row * 128 + kb * 8 + q * 2];
        float4 a1 = Xf4[row * 128 + kb * 8 + q * 2 + 1];
        f16x8 af;
        af[0] = (_Float16)a0.x; af[1] = (_Float16)a0.y;
        af[2] = (_Float16)a0.z; af[3] = (_Float16)a0.w;
        af[4] = (_Float16)a1.x; af[5] = (_Float16)a1.y;
        af[6] = (_Float16)a1.z; af[7] = (_Float16)a1.w;
        #pragma unroll
        for (int nt = 0; nt < 4; ++nt) {
            int col = nb * 64 + nt * 16 + r16;
            UU4 tmp; tmp.s = WpU4[(kb * 512 + col) * 4 + q];
            acc[nt] = __builtin_amdgcn_mfma_f32_16x16x32_f16(
                af, __builtin_bit_cast(f16x8, tmp.v), acc[nt], 0, 0, 0);
        }
    }

    const int rbase = mb * 64 + wave * 16 + q * 4;
    #pragma unroll
    for (int nt = 0; nt < 4; ++nt) {
        int col = nb * 64 + nt * 16 + r16;
        float bv = bias[col];
        #pragma unroll
        for (int rr = 0; rr < 4; ++rr) {
            out[(size_t)(rbase + rr) * 512 + col] = acc[nt][rr] + bv;
        }
    }
}

// ---------------------------------------------------------------------------
// Kernel 2 (v2): recurrence with 512 threads = 8 waves = 2 waves/SIMD.
// Rationale: per-SIMD MFMA pipe floor for the 512-col matvec is 128 MFMA x
// ~16 cyc = 2048 cyc/step; at 1 wave/SIMD the measured step was 4477 cyc —
// ~2400 cyc of exposed serial stalls (barrier vmcnt drain, ds_read latency,
// tanh tail). Two waves/SIMD interleave so one wave's stalls hide under the
// other's MFMA stream, at identical per-SIMD MFMA load.
// Wave w owns cols [w*64, w*64+64): 4 N-tiles x 16 k-blocks = 64 MFMA/step.
// B (W_hh): kb 0..11 register-resident (48 uint4 pinned to AGPR = 192 regs),
// kb 12..15 streamed from a 128 KB LDS image (stride-1 ds_read_b128).
// Per-wave regs ~240 < 256 -> 2 waves/SIMD fit. Each thread owns ONE output
// column c; acc tile nt == quad q holds it in reg 0 (A rows replicated).
// ---------------------------------------------------------------------------
__global__ __launch_bounds__(512, 2) void rnn_rec(const uint4* __restrict__ Wp4,
                                                  float* __restrict__ out) {
    extern __shared__ char smem[];
    uint4*  LBS = (uint4*)smem;                 // 8192 uint4 = 128 KB (kb 12..15)
    __half* hb  = (__half*)(smem + 131072);     // 2 x 512 halves (double buffer)

    const int b    = blockIdx.x;
    const int t    = threadIdx.x;    // 0..511
    const int lane = t & 63;
    const int w    = t >> 6;         // wave 0..7: owns cols [w*64, w*64+64)
    const int q    = lane >> 4;      // quad 0..3 (== this thread's N-tile)
    const int r16  = lane & 15;

    // Stage streamed B-fragments (k-blocks 12..15) into LDS.
    // Read layout: LBS[(s*4 + nt)*512 + t] -> stride-1 across the wave,
    // conflict-free ds_read_b128. Each thread stages its own 16 words.
    #pragma unroll
    for (int j = 0; j < 16; ++j) {
        int kb  = 12 + (j >> 2);
        int col = w * 64 + (j & 3) * 16 + r16;
        LBS[j * 512 + t] = Wp4[(kb * 512 + col) * 4 + q];
    }

    // Resident B-fragments: k-blocks 0..11 x 4 N-tiles = 48 uint4 / lane,
    // pinned to AGPRs (192 regs) to keep the VGPR file free for VALU work.
    u32x4 Bf[48];
    #pragma unroll
    for (int kb = 0; kb < 12; ++kb) {
        #pragma unroll
        for (int nt = 0; nt < 4; ++nt) {
            int col = w * 64 + nt * 16 + r16;
            UU4 tmp; tmp.s = Wp4[(kb * 512 + col) * 4 + q];
            Bf[kb * 4 + nt] = tmp.v;
        }
    }
    #pragma unroll
    for (int i = 0; i < 48; ++i) asm volatile("" : "+a"(Bf[i]));

    float* orow = out + (size_t)b * SEQ * DIM;
    const int c = w * 64 + q * 16 + r16;   // this thread's single output col

    // Step 0: h = tanh(xw).
    float xw = orow[c];
    float h  = tanh_fast(xw);
    orow[c] = h;
    hb[c] = __float2half(h);
    xw = orow[DIM + c];                    // prefetch step 1's xw
    __syncthreads();

    #pragma unroll 1
    for (int step = 1; step < SEQ; ++step) {
        orow += DIM;
        const __half* ha = hb + (((step & 1) ^ 1) << 9);   // h_{t-1}

        f32x4 m[4];
        #pragma unroll
        for (int i = 0; i < 4; ++i) m[i] = (f32x4){0.f, 0.f, 0.f, 0.f};

        // Streamed k-blocks first (LDS reads fill the pipe while MFMAs start).
        #pragma unroll
        for (int s = 0; s < 4; ++s) {
            f16x8 af = *(const f16x8*)(ha + (12 + s) * 32 + q * 8);
            #pragma unroll
            for (int nt = 0; nt < 4; ++nt) {
                UU4 tmp; tmp.s = LBS[(s * 4 + nt) * 512 + t];
                m[nt] = __builtin_amdgcn_mfma_f32_16x16x32_f16(
                    af, __builtin_bit_cast(f16x8, tmp.v), m[nt], 0, 0, 0);
            }
        }
        // Resident k-blocks.
        #pragma unroll
        for (int kb = 0; kb < 12; ++kb) {
            f16x8 af = *(const f16x8*)(ha + kb * 32 + q * 8);
            #pragma unroll
            for (int nt = 0; nt < 4; ++nt) {
                m[nt] = __builtin_amdgcn_mfma_f32_16x16x32_f16(
                    af, __builtin_bit_cast(f16x8, Bf[kb * 4 + nt]), m[nt], 0, 0, 0);
            }
        }

        // All acc rows equal (replicated A): tile q, reg 0 holds col c.
        float v = (q == 0 ? m[0][0] : q == 1 ? m[1][0] : q == 2 ? m[2][0] : m[3][0]) + xw;
        h = tanh_fast(v);

        orow[c] = h;
        __half* hw = hb + ((step & 1) << 9);
        hw[c] = __float2half(h);
        // Prefetch next xw (step 1023 reads into the h_final region: in-bounds,
        // value unused).
        xw = orow[DIM + c];
        __syncthreads();
    }

    float* hf = out + (size_t)BATCH * SEQ * DIM + (size_t)b * DIM;
    hf[c] = h;
}

extern "C" void kernel_launch(void* const* d_in, const int* in_sizes, int n_in,
                              void* d_out, int out_size, void* d_ws, size_t ws_size,
                              hipStream_t stream) {
    const float* X    = (const float*)d_in[0];   // [32,1024,512] fp32
    const float* Wxh  = (const float*)d_in[1];   // [512,512] fp32
    const float* Whh  = (const float*)d_in[2];   // [512,512] fp32
    const float* bias = (const float*)d_in[3];   // [512] fp32
    float* out = (float*)d_out;

    __half* WpXh = (__half*)d_ws;                          // 512 KB @ 0
    __half* WpHh = (__half*)((char*)d_ws + (512u << 10));  // 512 KB @ 512K

    (void)hipFuncSetAttribute((const void*)rnn_rec,
                              hipFuncAttributeMaxDynamicSharedMemorySize, 133120);

    pack_w<<<512, 512, 0, stream>>>(Wxh, WpXh);
    pack_w<<<512, 512, 0, stream>>>(Whh, WpHh);
    gemm_xw<<<dim3(8, 512), 256, 0, stream>>>(X, WpXh, bias, out);
    rnn_rec<<<BATCH, 512, 133120, stream>>>((const uint4*)WpHh, out);
}